// Round 9
// baseline (316.954 us; speedup 1.0000x reference)
//
#include <hip/hip_runtime.h>
#include <hip/hip_bf16.h>

// B=8, C_IN=C_OUT=64, H=W=64, K=3, N=9, PAD=1; padded coords in [0,65]
// f32 in, f32 out (verified R6-R8). Semantics identical to R5-R8 (verified).

typedef unsigned int u32;
typedef float f32x2 __attribute__((ext_vector_type(2)));

// ---------- K1: offset conv, one block per (b, h-pair) ----------
// 256 blocks x 512 threads (8 waves). Wave = 8-channel slice, BOTH h rows
// (weights s_load amortized over 2 rows of FMA). x read direct from global.
__global__ __launch_bounds__(512) void k1_offsets(
    const float* __restrict__ x,      // [8][64][64][64]
    const float* __restrict__ woff,   // [18][64][3][3]
    const float* __restrict__ boff,   // [18]
    float* __restrict__ offs) {       // [8][18][64][64]
  __shared__ float part[8 * 2 * 18 * 64];   // [wv][hh][o][w] 36864B

  int bh = blockIdx.x;              // 0..255
  int b  = bh >> 5;
  int h0 = (bh & 31) * 2;           // rows h0, h0+1
  int t  = threadIdx.x;
  int w  = t & 63;
  int wv = t >> 6;                  // 0..7
  bool lf = w > 0, rt = w < 63;

  float acc[2][18];
  #pragma unroll
  for (int hh = 0; hh < 2; ++hh)
    #pragma unroll
    for (int o = 0; o < 18; ++o) acc[hh][o] = 0.f;

  const float* xb = x + b * 262144;

  for (int cl = 0; cl < 8; ++cl) {
    int c = wv * 8 + cl;
    float v[4][3];                  // input rows h0-1 .. h0+2, cols w-1..w+1
    #pragma unroll
    for (int r = 0; r < 4; ++r) {
      int hin = h0 - 1 + r;
      bool vr = (hin >= 0 && hin < 64);
      const float* xr = xb + c * 4096 + hin * 64;
      v[r][0] = (vr && lf) ? xr[w - 1] : 0.f;
      v[r][1] = vr         ? xr[w]     : 0.f;
      v[r][2] = (vr && rt) ? xr[w + 1] : 0.f;
    }
    const float* wcb = woff + c * 9;
    #pragma unroll
    for (int o = 0; o < 18; ++o) {
      const float* wo = wcb + o * 576;
      float w0 = wo[0], w1 = wo[1], w2 = wo[2];
      float w3 = wo[3], w4 = wo[4], w5 = wo[5];
      float w6 = wo[6], w7 = wo[7], w8 = wo[8];
      acc[0][o] += v[0][0]*w0 + v[0][1]*w1 + v[0][2]*w2
                 + v[1][0]*w3 + v[1][1]*w4 + v[1][2]*w5
                 + v[2][0]*w6 + v[2][1]*w7 + v[2][2]*w8;
      acc[1][o] += v[1][0]*w0 + v[1][1]*w1 + v[1][2]*w2
                 + v[2][0]*w3 + v[2][1]*w4 + v[2][2]*w5
                 + v[3][0]*w6 + v[3][1]*w7 + v[3][2]*w8;
    }
  }

  #pragma unroll
  for (int hh = 0; hh < 2; ++hh)
    #pragma unroll
    for (int o = 0; o < 18; ++o)
      part[((wv * 2 + hh) * 18 + o) * 64 + w] = acc[hh][o];
  __syncthreads();

  for (int i = t; i < 2304; i += 512) {     // i = (hh*18 + o)*64 + ww
    int hh = i / 1152;
    int o  = (i >> 6) % 18;
    int ww = i & 63;
    float s = boff[o];
    #pragma unroll
    for (int pv = 0; pv < 8; ++pv)
      s += part[((pv * 2 + hh) * 18 + o) * 64 + ww];
    offs[b * 73728 + o * 4096 + (h0 + hh) * 64 + ww] = s;
  }
}

// ---------- K2: fused sample + final conv, one block per (b,h) ----------
// 512 blocks x 512 threads (8 waves). lane = w. Wave owns 8 co, 2 c per slice.
// Phase C folds corner validity into weights (invalid -> g=0, offset=0) and
// packs 4 element offsets; hot loop is branchless.
__global__ __launch_bounds__(512, 4) void k2_fused(
    const float* __restrict__ x,      // [8][64][64][64]
    const float* __restrict__ offs,   // [8][18][64][64]
    const float* __restrict__ wconv,  // [64][576]
    float* __restrict__ out) {        // [8][64][64][64]
  __shared__ float4 gw[9 * 64];       // [n][w] validity-folded bilinear weights
  __shared__ uint2  qo[9 * 64];       // [n][w] packed element offsets (lt|rb, lb|rt)
  __shared__ float  xo[144 * 66];     // [cl*9+n][w], w padded to 66

  int bh = blockIdx.x;
  int b = bh >> 6, h = bh & 63;
  int t = threadIdx.x;
  int wlane = t & 63;
  int wv = t >> 6;                    // 0..7
  int cobase = wv * 8;

  // ---- Phase C ----
  const float* offb = offs + b * 73728 + h * 64;
  for (int p = t; p < 576; p += 512) {
    int n  = p >> 6;                  // p = n*64 + w
    int ww = p & 63;
    float ox = offb[n * 4096 + ww];
    float oy = offb[(9 + n) * 4096 + ww];
    float px = (float)(h + (n / 3)) + ox;    // (h+1)+(n/3-1)+ox
    float py = (float)(ww + (n % 3)) + oy;
    float fx = floorf(px), fy = floorf(py);
    float pxc  = fminf(fmaxf(px, 0.f), 65.f);
    float pyc  = fminf(fmaxf(py, 0.f), 65.f);
    float fltx = fminf(fmaxf(fx, 0.f), 65.f);
    float flty = fminf(fmaxf(fy, 0.f), 65.f);
    float frbx = fminf(fmaxf(fx + 1.f, 0.f), 65.f);
    float frby = fminf(fmaxf(fy + 1.f, 0.f), 65.f);
    float ax = 1.f + fltx - pxc, bx = 1.f - frbx + pxc;
    float ay = 1.f + flty - pyc, by = 1.f - frby + pyc;
    float glt = ax * ay, grb = bx * by, glb = ax * by, grt = bx * ay;

    int ilt = (int)fltx, jlt = (int)flty, irb = (int)frbx, jrb = (int)frby;
    bool vlt = (ilt >= 1 && ilt <= 64 && jlt >= 1 && jlt <= 64);
    bool vrb = (irb >= 1 && irb <= 64 && jrb >= 1 && jrb <= 64);
    bool vlb = (ilt >= 1 && ilt <= 64 && jrb >= 1 && jrb <= 64);
    bool vrt = (irb >= 1 && irb <= 64 && jlt >= 1 && jlt <= 64);
    u32 o_lt = vlt ? (u32)((ilt - 1) * 64 + (jlt - 1)) : 0u;
    u32 o_rb = vrb ? (u32)((irb - 1) * 64 + (jrb - 1)) : 0u;
    u32 o_lb = vlb ? (u32)((ilt - 1) * 64 + (jrb - 1)) : 0u;
    u32 o_rt = vrt ? (u32)((irb - 1) * 64 + (jlt - 1)) : 0u;
    gw[p] = make_float4(vlt ? glt : 0.f, vrb ? grb : 0.f,
                        vlb ? glb : 0.f, vrt ? grt : 0.f);
    qo[p] = make_uint2(o_lt | (o_rb << 16), o_lb | (o_rt << 16));
  }
  __syncthreads();

  // cache this lane's 9 weight/offset records in registers (used by all 4 slices)
  float4 g[9];
  uint2  q[9];
  #pragma unroll
  for (int n = 0; n < 9; ++n) {
    g[n] = gw[n * 64 + wlane];
    q[n] = qo[n * 64 + wlane];
  }

  f32x2 acc2[8];
  #pragma unroll
  for (int i = 0; i < 8; ++i) acc2[i] = (f32x2){0.f, 0.f};

  const float*  xb = x + b * 262144;
  const float4* w4 = (const float4*)wconv;   // [64][144]

  for (int s = 0; s < 4; ++s) {
    // ---- sample: this thread covers c0 = s*16 + wv*2 and c0+1, its lane's w ----
    int c0 = s * 16 + wv * 2;
    const float* xcA = xb + c0 * 4096;
    const float* xcB = xcA + 4096;
    #pragma unroll
    for (int n = 0; n < 9; ++n) {
      u32 ua = q[n].x, ub = q[n].y;
      int olt = ua & 0xFFFF, orb = ua >> 16;
      int olb = ub & 0xFFFF, ort = ub >> 16;
      float4 gg = g[n];
      float vA = gg.x * xcA[olt] + gg.y * xcA[orb] + gg.z * xcA[olb] + gg.w * xcA[ort];
      float vB = gg.x * xcB[olt] + gg.y * xcB[orb] + gg.z * xcB[olb] + gg.w * xcB[ort];
      xo[((wv * 2 + 0) * 9 + n) * 66 + wlane] = vA;
      xo[((wv * 2 + 1) * 9 + n) * 66 + wlane] = vB;
    }
    __syncthreads();

    // ---- dot: acc2[i] += xo[k][wlane] . W[cobase+i][s*144 + k], float2 pairs ----
    for (int k4 = 0; k4 < 36; ++k4) {
      float xv0 = xo[(k4 * 4 + 0) * 66 + wlane];
      float xv1 = xo[(k4 * 4 + 1) * 66 + wlane];
      float xv2 = xo[(k4 * 4 + 2) * 66 + wlane];
      float xv3 = xo[(k4 * 4 + 3) * 66 + wlane];
      f32x2 xa = {xv0, xv1}, xc = {xv2, xv3};
      #pragma unroll
      for (int i = 0; i < 8; ++i) {
        float4 wr = w4[(cobase + i) * 144 + s * 36 + k4];
        acc2[i] += xa * (f32x2){wr.x, wr.y};
        acc2[i] += xc * (f32x2){wr.z, wr.w};
      }
    }
    __syncthreads();
  }

  float* ob = out + b * 262144 + h * 64 + wlane;
  #pragma unroll
  for (int i = 0; i < 8; ++i)
    ob[(cobase + i) * 4096] = acc2[i].x + acc2[i].y;
}

extern "C" void kernel_launch(void* const* d_in, const int* in_sizes, int n_in,
                              void* d_out, int out_size, void* d_ws, size_t ws_size,
                              hipStream_t stream) {
  const float *x = nullptr, *woff = nullptr, *boff = nullptr, *wconv = nullptr;
  for (int i = 0; i < n_in; ++i) {
    switch (in_sizes[i]) {
      case 2097152: x     = (const float*)d_in[i]; break;
      case 10368:   woff  = (const float*)d_in[i]; break;
      case 18:      boff  = (const float*)d_in[i]; break;
      case 36864:   wconv = (const float*)d_in[i]; break;
      default: break;
    }
  }
  if (!x)     x     = (const float*)d_in[0];
  if (!woff)  woff  = (const float*)d_in[1];
  if (!boff)  boff  = (const float*)d_in[2];
  if (!wconv) wconv = (const float*)d_in[3];
  float* out = (float*)d_out;

  float* offs = (float*)d_ws;   // 589824 floats = 2.36 MB

  k1_offsets<<<256, 512, 0, stream>>>(x, woff, boff, offs);
  k2_fused<<<512, 512, 0, stream>>>(x, offs, wconv, out);
}

// Round 10
// 181.571 us; speedup vs baseline: 1.7456x; 1.7456x over previous
//
#include <hip/hip_runtime.h>
#include <hip/hip_bf16.h>

// B=8, C_IN=C_OUT=64, H=W=64, K=3, N=9, PAD=1; padded coords in [0,65]
// f32 in, f32 out (verified R6-R9). Semantics identical to R5-R9 (verified).

typedef unsigned int u32;

// ---------- K1: offset conv, one block per (b, h-pair) ----------
// 256 blocks x 512 threads (8 waves). Wave = 8-channel slice, 2 h rows.
// All weights staged in LDS as [c][o][12] (pad 9->12 for aligned b128 reads,
// all-lane broadcast = conflict-free). x read direct from global (L2-hot).
// After the c-loop the weight LDS region is dead and is reused for the
// cross-wave partial reduction (two-step: waves 4-7 dump, waves 0-3 add).
__global__ __launch_bounds__(512) void k1_offsets(
    const float* __restrict__ x,      // [8][64][64][64]
    const float* __restrict__ woff,   // [18][64][3][3]
    const float* __restrict__ boff,   // [18]
    float* __restrict__ offs) {       // [8][18][64][64]
  __shared__ float lds[13824];        // 55296B: weights [c][o*12+k]; later partials

  int bh = blockIdx.x;                // 0..255
  int b  = bh >> 5;
  int h0 = (bh & 31) * 2;             // rows h0, h0+1
  int t  = threadIdx.x;
  int w  = t & 63;
  int wv = t >> 6;                    // 0..7
  bool lf = w > 0, rt = w < 63;

  // stage weights: woff[o][c][9] -> lds[c*216 + o*12 + k]
  for (int i = t; i < 10368; i += 512) {
    int o = i / 576;
    int c = (i / 9) % 64;
    int k = i % 9;
    lds[c * 216 + o * 12 + k] = woff[i];
  }
  __syncthreads();

  float acc[2][18];
  #pragma unroll
  for (int hh = 0; hh < 2; ++hh)
    #pragma unroll
    for (int o = 0; o < 18; ++o) acc[hh][o] = 0.f;

  const float* xb = x + b * 262144;

  for (int cl = 0; cl < 8; ++cl) {
    int c = wv * 8 + cl;
    float v[4][3];                    // input rows h0-1..h0+2, cols w-1..w+1
    #pragma unroll
    for (int r = 0; r < 4; ++r) {
      int hin = h0 - 1 + r;
      bool vr = (hin >= 0 && hin < 64);
      const float* xr = xb + c * 4096 + hin * 64;
      v[r][0] = (vr && lf) ? xr[w - 1] : 0.f;
      v[r][1] = vr         ? xr[w]     : 0.f;
      v[r][2] = (vr && rt) ? xr[w + 1] : 0.f;
    }
    const float4* wbase = (const float4*)(lds + c * 216);
    #pragma unroll
    for (int o = 0; o < 18; ++o) {
      float4 wa = wbase[o * 3 + 0];   // w0..w3
      float4 wb = wbase[o * 3 + 1];   // w4..w7
      float4 wc = wbase[o * 3 + 2];   // w8 (.x)
      acc[0][o] += v[0][0]*wa.x + v[0][1]*wa.y + v[0][2]*wa.z
                 + v[1][0]*wa.w + v[1][1]*wb.x + v[1][2]*wb.y
                 + v[2][0]*wb.z + v[2][1]*wb.w + v[2][2]*wc.x;
      acc[1][o] += v[1][0]*wa.x + v[1][1]*wa.y + v[1][2]*wa.z
                 + v[2][0]*wa.w + v[2][1]*wb.x + v[2][2]*wb.y
                 + v[3][0]*wb.z + v[3][1]*wb.w + v[3][2]*wc.x;
    }
  }
  __syncthreads();   // weights dead; reuse lds for partials (4 regions x 9216B)

  // step 1: waves 4-7 dump partials into region (wv-4)
  if (wv >= 4) {
    float* reg = lds + (wv - 4) * 2304;       // [hh][o][w] 2304 floats
    #pragma unroll
    for (int hh = 0; hh < 2; ++hh)
      #pragma unroll
      for (int o = 0; o < 18; ++o)
        reg[(hh * 18 + o) * 64 + w] = acc[hh][o];
  }
  __syncthreads();
  // step 2: waves 0-3 add counterpart, write back into region wv
  if (wv < 4) {
    float* reg = lds + wv * 2304;
    #pragma unroll
    for (int hh = 0; hh < 2; ++hh)
      #pragma unroll
      for (int o = 0; o < 18; ++o) {
        int idx = (hh * 18 + o) * 64 + w;
        reg[idx] += acc[hh][o];
      }
  }
  __syncthreads();
  // step 3: sum 4 regions + bias -> global
  for (int i = t; i < 2304; i += 512) {       // i = (hh*18+o)*64 + ww
    int hh = i / 1152;
    int o  = (i >> 6) % 18;
    int ww = i & 63;
    float s = lds[i] + lds[2304 + i] + lds[4608 + i] + lds[6912 + i] + boff[o];
    offs[b * 73728 + o * 4096 + (h0 + hh) * 64 + ww] = s;
  }
}

// ---------- K2: fused sample + final conv, one block per (b,h) ----------
// EXACT R8 version (114us, VGPR 40, no spills). 512 blocks x 512 threads.
__global__ __launch_bounds__(512) void k2_fused(
    const float* __restrict__ x,      // [8][64][64][64]
    const float* __restrict__ offs,   // [8][18][64][64]
    const float* __restrict__ wconv,  // [64][576]
    float* __restrict__ out) {        // [8][64][64][64]
  __shared__ float4 gw_t[9 * 64];     // [n][w] bilinear weights (lt, rb, lb, rt)
  __shared__ u32    qq_t[9 * 64];     // [n][w] packed clamped corners
  __shared__ float  xo[144 * 66];     // slice samples [cl*9+n][w], w padded to 66

  int bh = blockIdx.x;
  int b = bh >> 6, h = bh & 63;
  int t = threadIdx.x;
  int wlane = t & 63;
  int wv = __builtin_amdgcn_readfirstlane(t >> 6);   // 0..7
  int cobase = wv * 8;

  // ---- Phase C: corners + bilinear weights per (w, n), transposed [n][w] ----
  const float* offb = offs + b * 73728 + h * 64;
  for (int p = t; p < 576; p += 512) {
    int n  = p >> 6;       // p = n*64 + w
    int ww = p & 63;
    float ox = offb[n * 4096 + ww];
    float oy = offb[(9 + n) * 4096 + ww];
    float px = (float)(h + (n / 3)) + ox;   // (h+1)+(n/3-1)+ox
    float py = (float)(ww + (n % 3)) + oy;
    float fx = floorf(px), fy = floorf(py);
    float pxc  = fminf(fmaxf(px, 0.f), 65.f);
    float pyc  = fminf(fmaxf(py, 0.f), 65.f);
    float fltx = fminf(fmaxf(fx, 0.f), 65.f);
    float flty = fminf(fmaxf(fy, 0.f), 65.f);
    float frbx = fminf(fmaxf(fx + 1.f, 0.f), 65.f);
    float frby = fminf(fmaxf(fy + 1.f, 0.f), 65.f);
    float ax = 1.f + fltx - pxc, bx = 1.f - frbx + pxc;
    float ay = 1.f + flty - pyc, by = 1.f - frby + pyc;
    gw_t[p] = make_float4(ax * ay, bx * by, ax * by, bx * ay);  // glt, grb, glb, grt
    qq_t[p] = (u32)fltx | ((u32)flty << 8) | ((u32)frbx << 16) | ((u32)frby << 24);
  }
  __syncthreads();

  float acc[8];
  #pragma unroll
  for (int i = 0; i < 8; ++i) acc[i] = 0.f;

  const float*  xb = x + b * 262144;
  const float4* w4 = (const float4*)wconv;   // [64][144]

  for (int s = 0; s < 4; ++s) {
    // ---- sample slice s: channels s*16 .. s*16+15; 2 c per thread ----
    for (int n = 0; n < 9; ++n) {
      float4 g = gw_t[n * 64 + wlane];
      u32 q    = qq_t[n * 64 + wlane];
      int ilt = q & 255, jlt = (q >> 8) & 255, irb = (q >> 16) & 255, jrb = q >> 24;
      bool vi_lt = (ilt >= 1 && ilt <= 64), vj_lt = (jlt >= 1 && jlt <= 64);
      bool vi_rb = (irb >= 1 && irb <= 64), vj_rb = (jrb >= 1 && jrb <= 64);
      int o_lt = (ilt - 1) * 64 + (jlt - 1);
      int o_rb = (irb - 1) * 64 + (jrb - 1);
      int o_lb = (ilt - 1) * 64 + (jrb - 1);
      int o_rt = (irb - 1) * 64 + (jlt - 1);
      #pragma unroll
      for (int j = 0; j < 2; ++j) {
        int cl = wv * 2 + j;            // 0..15
        const float* xc = xb + (s * 16 + cl) * 4096;
        float vlt = (vi_lt && vj_lt) ? xc[o_lt] : 0.f;
        float vrb = (vi_rb && vj_rb) ? xc[o_rb] : 0.f;
        float vlb = (vi_lt && vj_rb) ? xc[o_lb] : 0.f;
        float vrt = (vi_rb && vj_lt) ? xc[o_rt] : 0.f;
        xo[(cl * 9 + n) * 66 + wlane] = g.x * vlt + g.y * vrb + g.z * vlb + g.w * vrt;
      }
    }
    __syncthreads();

    // ---- dot: acc[i] += xo[k][wlane] . W[cobase+i][s*144 + k] ----
    for (int k4 = 0; k4 < 36; ++k4) {
      float xv0 = xo[(k4 * 4 + 0) * 66 + wlane];
      float xv1 = xo[(k4 * 4 + 1) * 66 + wlane];
      float xv2 = xo[(k4 * 4 + 2) * 66 + wlane];
      float xv3 = xo[(k4 * 4 + 3) * 66 + wlane];
      #pragma unroll
      for (int i = 0; i < 8; ++i) {
        float4 wr = w4[(cobase + i) * 144 + s * 36 + k4];
        acc[i] += xv0 * wr.x + xv1 * wr.y + xv2 * wr.z + xv3 * wr.w;
      }
    }
    __syncthreads();
  }

  float* ob = out + b * 262144 + h * 64 + wlane;
  #pragma unroll
  for (int i = 0; i < 8; ++i)
    ob[(cobase + i) * 4096] = acc[i];
}

extern "C" void kernel_launch(void* const* d_in, const int* in_sizes, int n_in,
                              void* d_out, int out_size, void* d_ws, size_t ws_size,
                              hipStream_t stream) {
  const float *x = nullptr, *woff = nullptr, *boff = nullptr, *wconv = nullptr;
  for (int i = 0; i < n_in; ++i) {
    switch (in_sizes[i]) {
      case 2097152: x     = (const float*)d_in[i]; break;
      case 10368:   woff  = (const float*)d_in[i]; break;
      case 18:      boff  = (const float*)d_in[i]; break;
      case 36864:   wconv = (const float*)d_in[i]; break;
      default: break;
    }
  }
  if (!x)     x     = (const float*)d_in[0];
  if (!woff)  woff  = (const float*)d_in[1];
  if (!boff)  boff  = (const float*)d_in[2];
  if (!wconv) wconv = (const float*)d_in[3];
  float* out = (float*)d_out;

  float* offs = (float*)d_ws;   // 589824 floats = 2.36 MB

  k1_offsets<<<256, 512, 0, stream>>>(x, woff, boff, offs);
  k2_fused<<<512, 512, 0, stream>>>(x, offs, wconv, out);
}

// Round 11
// 179.107 us; speedup vs baseline: 1.7696x; 1.0138x over previous
//
#include <hip/hip_runtime.h>
#include <hip/hip_bf16.h>

// B=8, C_IN=C_OUT=64, H=W=64, K=3, N=9, PAD=1; padded coords in [0,65]
// f32 in, f32 out. Semantics identical to R5-R10 (verified).
// Single fused kernel: one block per (b,h). 512 blocks x 512 threads (8 waves).
//   A: stage x rows h-1..h+1 (all 64 c) into LDS (zero-padded rows)
//   B: offset conv, c-split across waves (wave wv owns 8 channels, partial
//      acc[18] per lane=w), 8-region LDS tree reduction -> offs_s[18][64]
//   C: per-(w,n) corners + bilinear weights -> gw/qq   (R8 code, LDS source)
//   D: 4 slices of 16 c: sample into xo (aliasing dead xs) + dot vs W_conv
//      (R8 code verbatim: VGPR 40, no spills)

typedef unsigned int u32;

__global__ __launch_bounds__(512) void deform_one(
    const float* __restrict__ x,      // [8][64][64][64]
    const float* __restrict__ woff,   // [18][64][3][3]
    const float* __restrict__ boff,   // [18]
    const float* __restrict__ wconv,  // [64][576]
    float* __restrict__ out) {        // [8][64][64][64]
  __shared__ float  buf[12288];       // 49152B: xs[3][64][64] -> partials[8][18][64] -> xo[144][66]
  __shared__ float4 gw[576];          // 9216B  [n][w]
  __shared__ u32    qq[576];          // 2304B  [n][w]
  __shared__ float  offs_s[1152];     // 4608B  [o][w]           total 65280B

  int bh = blockIdx.x;
  int b = bh >> 6, h = bh & 63;
  int t = threadIdx.x;
  int wlane = t & 63;
  int wv = __builtin_amdgcn_readfirstlane(t >> 6);   // 0..7
  const float* xb = x + b * 262144;

  // ---- Phase A: stage 3 rows x 64 c x 64 w, float4-coalesced ----
  {
    float4* b4 = (float4*)buf;
    for (int i = t; i < 3072; i += 512) {        // i*4 = kh*4096 + c*64 + w
      int kh = i >> 10;
      int rest = i & 1023;
      int c  = rest >> 4;
      int w4 = rest & 15;
      int hh = h + kh - 1;
      float4 v = make_float4(0.f, 0.f, 0.f, 0.f);
      if (hh >= 0 && hh < 64)
        v = ((const float4*)(xb + c * 4096 + hh * 64))[w4];
      b4[i] = v;
    }
  }
  __syncthreads();

  // ---- Phase B: offset conv, wave wv owns channels [8wv, 8wv+8) ----
  {
    int w = wlane;
    bool lf = w > 0, rt = w < 63;
    float acc[18];
    #pragma unroll
    for (int o = 0; o < 18; ++o) acc[o] = 0.f;

    for (int cl = 0; cl < 8; ++cl) {
      int c = wv * 8 + cl;
      float v[9];                                // [kh][kw]
      #pragma unroll
      for (int kh = 0; kh < 3; ++kh) {
        const float* row = buf + kh * 4096 + c * 64;
        v[kh * 3 + 0] = lf ? row[w - 1] : 0.f;
        v[kh * 3 + 1] = row[w];
        v[kh * 3 + 2] = rt ? row[w + 1] : 0.f;
      }
      const float* wc = woff + c * 9;            // + o*576, wave-uniform -> s_load
      #pragma unroll
      for (int o = 0; o < 18; ++o) {
        const float* wo = wc + o * 576;
        acc[o] += v[0]*wo[0] + v[1]*wo[1] + v[2]*wo[2]
                + v[3]*wo[3] + v[4]*wo[4] + v[5]*wo[5]
                + v[6]*wo[6] + v[7]*wo[7] + v[8]*wo[8];
      }
    }
    __syncthreads();   // xs reads done; buf reusable as partials[8][18][64]

    float* part = buf + wv * 1152;
    #pragma unroll
    for (int o = 0; o < 18; ++o)
      part[o * 64 + w] = acc[o];
  }
  __syncthreads();

  // final sum of 8 partials + bias -> offs_s[o][w]
  for (int i = t; i < 1152; i += 512) {
    int o = i >> 6;
    float s = boff[o];
    #pragma unroll
    for (int p = 0; p < 8; ++p) s += buf[p * 1152 + i];
    offs_s[i] = s;
  }
  __syncthreads();

  // ---- Phase C: corners + bilinear weights per (w, n), transposed [n][w] ----
  for (int p = t; p < 576; p += 512) {
    int n  = p >> 6;       // p = n*64 + w
    int ww = p & 63;
    float ox = offs_s[n * 64 + ww];
    float oy = offs_s[(9 + n) * 64 + ww];
    float px = (float)(h + (n / 3)) + ox;   // (h+1)+(n/3-1)+ox
    float py = (float)(ww + (n % 3)) + oy;
    float fx = floorf(px), fy = floorf(py);
    float pxc  = fminf(fmaxf(px, 0.f), 65.f);
    float pyc  = fminf(fmaxf(py, 0.f), 65.f);
    float fltx = fminf(fmaxf(fx, 0.f), 65.f);
    float flty = fminf(fmaxf(fy, 0.f), 65.f);
    float frbx = fminf(fmaxf(fx + 1.f, 0.f), 65.f);
    float frby = fminf(fmaxf(fy + 1.f, 0.f), 65.f);
    float ax = 1.f + fltx - pxc, bx = 1.f - frbx + pxc;
    float ay = 1.f + flty - pyc, by = 1.f - frby + pyc;
    gw[p] = make_float4(ax * ay, bx * by, ax * by, bx * ay);  // glt, grb, glb, grt
    qq[p] = (u32)fltx | ((u32)flty << 8) | ((u32)frbx << 16) | ((u32)frby << 24);
  }
  __syncthreads();

  // ---- Phase D: sample + dot (R8 code; xo aliases buf) ----
  float acc[8];
  #pragma unroll
  for (int i = 0; i < 8; ++i) acc[i] = 0.f;
  int cobase = wv * 8;
  float* xo = buf;                           // [144][66] = 9504 floats
  const float4* w4 = (const float4*)wconv;   // [64][144]

  for (int s = 0; s < 4; ++s) {
    for (int n = 0; n < 9; ++n) {
      float4 g = gw[n * 64 + wlane];
      u32 q    = qq[n * 64 + wlane];
      int ilt = q & 255, jlt = (q >> 8) & 255, irb = (q >> 16) & 255, jrb = q >> 24;
      bool vi_lt = (ilt >= 1 && ilt <= 64), vj_lt = (jlt >= 1 && jlt <= 64);
      bool vi_rb = (irb >= 1 && irb <= 64), vj_rb = (jrb >= 1 && jrb <= 64);
      int o_lt = (ilt - 1) * 64 + (jlt - 1);
      int o_rb = (irb - 1) * 64 + (jrb - 1);
      int o_lb = (ilt - 1) * 64 + (jrb - 1);
      int o_rt = (irb - 1) * 64 + (jlt - 1);
      #pragma unroll
      for (int j = 0; j < 2; ++j) {
        int cl = wv * 2 + j;            // 0..15
        const float* xc = xb + (s * 16 + cl) * 4096;
        float vlt = (vi_lt && vj_lt) ? xc[o_lt] : 0.f;
        float vrb = (vi_rb && vj_rb) ? xc[o_rb] : 0.f;
        float vlb = (vi_lt && vj_rb) ? xc[o_lb] : 0.f;
        float vrt = (vi_rb && vj_lt) ? xc[o_rt] : 0.f;
        xo[(cl * 9 + n) * 66 + wlane] = g.x * vlt + g.y * vrb + g.z * vlb + g.w * vrt;
      }
    }
    __syncthreads();

    for (int k4 = 0; k4 < 36; ++k4) {
      float xv0 = xo[(k4 * 4 + 0) * 66 + wlane];
      float xv1 = xo[(k4 * 4 + 1) * 66 + wlane];
      float xv2 = xo[(k4 * 4 + 2) * 66 + wlane];
      float xv3 = xo[(k4 * 4 + 3) * 66 + wlane];
      #pragma unroll
      for (int i = 0; i < 8; ++i) {
        float4 wr = w4[(cobase + i) * 144 + s * 36 + k4];
        acc[i] += xv0 * wr.x + xv1 * wr.y + xv2 * wr.z + xv3 * wr.w;
      }
    }
    __syncthreads();
  }

  float* ob = out + b * 262144 + h * 64 + wlane;
  #pragma unroll
  for (int i = 0; i < 8; ++i)
    ob[(cobase + i) * 4096] = acc[i];
}

extern "C" void kernel_launch(void* const* d_in, const int* in_sizes, int n_in,
                              void* d_out, int out_size, void* d_ws, size_t ws_size,
                              hipStream_t stream) {
  const float *x = nullptr, *woff = nullptr, *boff = nullptr, *wconv = nullptr;
  for (int i = 0; i < n_in; ++i) {
    switch (in_sizes[i]) {
      case 2097152: x     = (const float*)d_in[i]; break;
      case 10368:   woff  = (const float*)d_in[i]; break;
      case 18:      boff  = (const float*)d_in[i]; break;
      case 36864:   wconv = (const float*)d_in[i]; break;
      default: break;
    }
  }
  if (!x)     x     = (const float*)d_in[0];
  if (!woff)  woff  = (const float*)d_in[1];
  if (!boff)  boff  = (const float*)d_in[2];
  if (!wconv) wconv = (const float*)d_in[3];
  float* out = (float*)d_out;

  deform_one<<<512, 512, 0, stream>>>(x, woff, boff, wconv, out);
}

// Round 12
// 175.024 us; speedup vs baseline: 1.8109x; 1.0233x over previous
//
#include <hip/hip_runtime.h>
#include <hip/hip_bf16.h>

// B=8, C_IN=C_OUT=64, H=W=64, K=3, N=9, PAD=1; padded coords in [0,65]
// f32 in, f32 out. Semantics identical to R5-R11 (verified).
// R12: Phase-D dot -> bf16 MFMA (16x16x32), K split as 2 slices of 32 c.
//   k0: W_conv -> bf16 B-fragment order in ws; W_off -> [c][o][12] f32 in ws.
//   xo staged in LDS as bf16 [w][k] (stride 296, 16B-aligned rows) = A-frags.

typedef unsigned int u32;
typedef unsigned short u16;
typedef short s8v __attribute__((ext_vector_type(8)));     // 8 bf16 (4 VGPR)
typedef float f4v __attribute__((ext_vector_type(4)));     // MFMA acc

__device__ __forceinline__ u16 f2bf(float f) {
  u32 u = __builtin_bit_cast(u32, f);
  u32 r = (u + 0x7FFFu + ((u >> 16) & 1u)) >> 16;   // RNE, finite inputs
  return (u16)r;
}

// ---------- k0: weight prep ----------
// wfrag[nt][ks][lane][j] bf16: B-fragment for mfma_16x16x32_bf16
//   co = nt*16 + (lane&15), k = ks*32 + (lane>>4)*8 + j   (k = c*9+n order)
// woff_r[c][o][12] f32 (9 used, pad 12 for float4 alignment)
__global__ __launch_bounds__(256) void k0_prep(
    const float* __restrict__ wconv,  // [64][576]
    const float* __restrict__ woff,   // [18][64][9]
    u16* __restrict__ wfrag,          // 4*18*64*8 = 36864 bf16
    float* __restrict__ woff_r) {     // 64*216 f32
  int tid = blockIdx.x * 256 + threadIdx.x;   // grid 72*256 = 18432
  if (tid < 4608) {
    int nt = tid / 1152, ks = (tid / 64) % 18, lane = tid & 63;
    int co = nt * 16 + (lane & 15);
    int k0 = ks * 32 + ((lane >> 4) << 3);
    const float* src = wconv + co * 576 + k0;
    u16* dst = wfrag + tid * 8;
    #pragma unroll
    for (int j = 0; j < 8; ++j) dst[j] = f2bf(src[j]);
  }
  if (tid < 10368) {
    int o = tid / 576, c = (tid / 9) % 64, k = tid % 9;
    woff_r[c * 216 + o * 12 + k] = woff[tid];
  }
}

// ---------- fused main: one block per (b,h), 512 blocks x 512 threads ----------
__global__ __launch_bounds__(512) void deform_one(
    const float* __restrict__ x,        // [8][64][64][64]
    const float* __restrict__ woff_r,   // [64][18][12] f32
    const float* __restrict__ boff,     // [18]
    const u16*  __restrict__ wfrag,     // B-fragments bf16
    float* __restrict__ out) {          // [8][64][64][64]
  __shared__ float  buf[12288];   // 49152B: xs[3][64][64] -> partials[8][18][64] -> xo bf16 [64][296]
  __shared__ float4 gw[576];      // 9216B [n][w] validity-folded bilinear weights
  __shared__ u32    qq[576];      // 2304B [n][w] packed 0-based corner coords
  __shared__ float  offs_s[1152]; // 4608B [o][w]      total 65280B

  int bh = blockIdx.x;
  int b = bh >> 6, h = bh & 63;
  int t = threadIdx.x;
  int wlane = t & 63;
  int wv = __builtin_amdgcn_readfirstlane(t >> 6);   // 0..7
  const float* xb = x + b * 262144;

  // ---- Phase A: stage x rows h-1..h+1, all 64 c, float4-coalesced ----
  {
    float4* b4 = (float4*)buf;
    for (int i = t; i < 3072; i += 512) {
      int kh = i >> 10;
      int rest = i & 1023;
      int c  = rest >> 4;
      int w4 = rest & 15;
      int hh = h + kh - 1;
      float4 v = make_float4(0.f, 0.f, 0.f, 0.f);
      if (hh >= 0 && hh < 64)
        v = ((const float4*)(xb + c * 4096 + hh * 64))[w4];
      b4[i] = v;
    }
  }
  __syncthreads();

  // ---- Phase B: offset conv, wave wv owns channels [8wv, 8wv+8) ----
  {
    int w = wlane;
    bool lf = w > 0, rt = w < 63;
    float acc[18];
    #pragma unroll
    for (int o = 0; o < 18; ++o) acc[o] = 0.f;

    for (int cl = 0; cl < 8; ++cl) {
      int c = wv * 8 + cl;
      float v[9];
      #pragma unroll
      for (int kh = 0; kh < 3; ++kh) {
        const float* row = buf + kh * 4096 + c * 64;
        v[kh * 3 + 0] = lf ? row[w - 1] : 0.f;
        v[kh * 3 + 1] = row[w];
        v[kh * 3 + 2] = rt ? row[w + 1] : 0.f;
      }
      const float4* wc4 = (const float4*)(woff_r + c * 216);  // wave-uniform -> s_load
      #pragma unroll
      for (int o = 0; o < 18; ++o) {
        float4 wa = wc4[o * 3 + 0];
        float4 wb = wc4[o * 3 + 1];
        float4 wcv = wc4[o * 3 + 2];
        acc[o] += v[0]*wa.x + v[1]*wa.y + v[2]*wa.z + v[3]*wa.w
                + v[4]*wb.x + v[5]*wb.y + v[6]*wb.z + v[7]*wb.w
                + v[8]*wcv.x;
      }
    }
    __syncthreads();   // xs reads done; buf -> partials[8][18][64]
    float* part = buf + wv * 1152;
    #pragma unroll
    for (int o = 0; o < 18; ++o)
      part[o * 64 + w] = acc[o];
  }
  __syncthreads();

  for (int i = t; i < 1152; i += 512) {
    int o = i >> 6;
    float s = boff[o];
    #pragma unroll
    for (int p = 0; p < 8; ++p) s += buf[p * 1152 + i];
    offs_s[i] = s;
  }
  __syncthreads();

  // ---- Phase C: corners + bilinear weights, validity folded ----
  for (int p = t; p < 576; p += 512) {
    int n  = p >> 6;       // p = n*64 + w
    int ww = p & 63;
    float ox = offs_s[n * 64 + ww];
    float oy = offs_s[(9 + n) * 64 + ww];
    float px = (float)(h + (n / 3)) + ox;   // (h+1)+(n/3-1)+ox
    float py = (float)(ww + (n % 3)) + oy;
    float fx = floorf(px), fy = floorf(py);
    float pxc  = fminf(fmaxf(px, 0.f), 65.f);
    float pyc  = fminf(fmaxf(py, 0.f), 65.f);
    float fltx = fminf(fmaxf(fx, 0.f), 65.f);
    float flty = fminf(fmaxf(fy, 0.f), 65.f);
    float frbx = fminf(fmaxf(fx + 1.f, 0.f), 65.f);
    float frby = fminf(fmaxf(fy + 1.f, 0.f), 65.f);
    float ax = 1.f + fltx - pxc, bx = 1.f - frbx + pxc;
    float ay = 1.f + flty - pyc, by = 1.f - frby + pyc;
    float glt = ax * ay, grb = bx * by, glb = ax * by, grt = bx * ay;

    int ilt = (int)fltx, jlt = (int)flty, irb = (int)frbx, jrb = (int)frby;
    bool bi0 = (ilt >= 1 && ilt <= 64), bj0 = (jlt >= 1 && jlt <= 64);
    bool bi1 = (irb >= 1 && irb <= 64), bj1 = (jrb >= 1 && jrb <= 64);
    u32 i0 = bi0 ? (u32)(ilt - 1) : 0u;
    u32 j0 = bj0 ? (u32)(jlt - 1) : 0u;
    u32 i1 = bi1 ? (u32)(irb - 1) : 0u;
    u32 j1 = bj1 ? (u32)(jrb - 1) : 0u;
    gw[p] = make_float4((bi0 && bj0) ? glt : 0.f, (bi1 && bj1) ? grb : 0.f,
                        (bi0 && bj1) ? glb : 0.f, (bi1 && bj0) ? grt : 0.f);
    qq[p] = i0 | (j0 << 8) | (i1 << 16) | (j1 << 24);
  }
  __syncthreads();

  // ---- Phase D: 2 slices of 32 c: sample -> xo bf16 [w][k], MFMA dot ----
  u16* xow = (u16*)buf;                 // [64][296], row stride 296 bf16 (592B)
  int m0 = wv & 3;                      // w-tile
  int n0 = (wv >> 2) * 2;               // co-tiles n0, n0+1
  int aoff = (m0 * 16 + (wlane & 15)) * 296 + ((wlane >> 4) << 3);
  const s8v* Wf = (const s8v*)wfrag;    // [(nt*18+ks)*64 + lane]
  f4v acc0 = {0.f, 0.f, 0.f, 0.f}, acc1 = {0.f, 0.f, 0.f, 0.f};

  for (int s = 0; s < 2; ++s) {
    // sample: thread covers c_l = wv*4 .. wv*4+3, its lane's w, all 9 n
    int c_l0 = wv * 4;
    const float* xc0 = xb + (s * 32 + c_l0) * 4096;
    for (int n = 0; n < 9; ++n) {
      float4 g = gw[n * 64 + wlane];
      u32 q    = qq[n * 64 + wlane];
      int i0 = q & 255, j0 = (q >> 8) & 255, i1 = (q >> 16) & 255, j1 = q >> 24;
      int olt = i0 * 64 + j0, orb = i1 * 64 + j1;
      int olb = i0 * 64 + j1, ort = i1 * 64 + j0;
      #pragma unroll
      for (int j = 0; j < 4; ++j) {
        const float* xc = xc0 + j * 4096;
        float v = g.x * xc[olt] + g.y * xc[orb] + g.z * xc[olb] + g.w * xc[ort];
        xow[wlane * 296 + (c_l0 + j) * 9 + n] = f2bf(v);
      }
    }
    __syncthreads();

    // dot: 9 K-steps of 32; A from LDS (b128), B from global (coalesced 16B/lane)
    #pragma unroll
    for (int ksl = 0; ksl < 9; ++ksl) {
      s8v a = *(const s8v*)(xow + aoff + ksl * 32);
      int ks = s * 9 + ksl;
      s8v b0 = Wf[(n0 * 18 + ks) * 64 + wlane];
      s8v b1 = Wf[((n0 + 1) * 18 + ks) * 64 + wlane];
      acc0 = __builtin_amdgcn_mfma_f32_16x16x32_bf16(a, b0, acc0, 0, 0, 0);
      acc1 = __builtin_amdgcn_mfma_f32_16x16x32_bf16(a, b1, acc1, 0, 0, 0);
    }
    __syncthreads();
  }

  // ---- store: D layout col=lane&15 (co-local), row=quad*4+reg (w-local) ----
  float* ob = out + b * 262144 + h * 64;
  int quad = wlane >> 4;
  int w_b  = m0 * 16 + quad * 4;
  int co0  = n0 * 16 + (wlane & 15);
  int co1  = co0 + 16;
  #pragma unroll
  for (int r = 0; r < 4; ++r) {
    ob[co0 * 4096 + w_b + r] = acc0[r];
    ob[co1 * 4096 + w_b + r] = acc1[r];
  }
}

extern "C" void kernel_launch(void* const* d_in, const int* in_sizes, int n_in,
                              void* d_out, int out_size, void* d_ws, size_t ws_size,
                              hipStream_t stream) {
  const float *x = nullptr, *woff = nullptr, *boff = nullptr, *wconv = nullptr;
  for (int i = 0; i < n_in; ++i) {
    switch (in_sizes[i]) {
      case 2097152: x     = (const float*)d_in[i]; break;
      case 10368:   woff  = (const float*)d_in[i]; break;
      case 18:      boff  = (const float*)d_in[i]; break;
      case 36864:   wconv = (const float*)d_in[i]; break;
      default: break;
    }
  }
  if (!x)     x     = (const float*)d_in[0];
  if (!woff)  woff  = (const float*)d_in[1];
  if (!boff)  boff  = (const float*)d_in[2];
  if (!wconv) wconv = (const float*)d_in[3];
  float* out = (float*)d_out;

  u16*   wfrag  = (u16*)d_ws;                       // 73728 B
  float* woff_r = (float*)((char*)d_ws + 73728);    // 55296 B

  k0_prep<<<72, 256, 0, stream>>>(wconv, woff, wfrag, woff_r);
  deform_one<<<512, 512, 0, stream>>>(x, woff_r, boff, wfrag, out);
}

// Round 13
// 167.004 us; speedup vs baseline: 1.8979x; 1.0480x over previous
//
#include <hip/hip_runtime.h>
#include <hip/hip_bf16.h>

// B=8, C_IN=C_OUT=64, H=W=64, K=3, N=9, PAD=1; padded coords in [0,65]
// f32 in, f32 out. Semantics identical to R5-R12 (verified).
// R13: drop Phase-A LDS staging (Phase B reads x direct from global,
// near-coalesced, L1/L2-hot) -> LDS 54016B -> 3 blocks/CU (was 2).
// Phase C/D = verified R12 MFMA path.

typedef unsigned int u32;
typedef unsigned short u16;
typedef short s8v __attribute__((ext_vector_type(8)));     // 8 bf16 (4 VGPR)
typedef float f4v __attribute__((ext_vector_type(4)));     // MFMA acc

__device__ __forceinline__ u16 f2bf(float f) {
  u32 u = __builtin_bit_cast(u32, f);
  u32 r = (u + 0x7FFFu + ((u >> 16) & 1u)) >> 16;   // RNE, finite inputs
  return (u16)r;
}

// ---------- k0: weight prep ----------
// wfrag[nt][ks][lane][j] bf16: B-fragment for mfma_16x16x32_bf16
//   co = nt*16 + (lane&15), k = ks*32 + (lane>>4)*8 + j   (k = c*9+n order)
// woff_r[c][o][12] f32 (9 used, pad 12 for float4 alignment)
__global__ __launch_bounds__(256) void k0_prep(
    const float* __restrict__ wconv,  // [64][576]
    const float* __restrict__ woff,   // [18][64][9]
    u16* __restrict__ wfrag,          // 4*18*64*8 = 36864 bf16
    float* __restrict__ woff_r) {     // 64*216 f32
  int tid = blockIdx.x * 256 + threadIdx.x;   // grid 72*256 = 18432
  if (tid < 4608) {
    int nt = tid / 1152, ks = (tid / 64) % 18, lane = tid & 63;
    int co = nt * 16 + (lane & 15);
    int k0 = ks * 32 + ((lane >> 4) << 3);
    const float* src = wconv + co * 576 + k0;
    u16* dst = wfrag + tid * 8;
    #pragma unroll
    for (int j = 0; j < 8; ++j) dst[j] = f2bf(src[j]);
  }
  if (tid < 10368) {
    int o = tid / 576, c = (tid / 9) % 64, k = tid % 9;
    woff_r[c * 216 + o * 12 + k] = woff[tid];
  }
}

// ---------- fused main: one block per (b,h), 512 blocks x 512 threads ----------
__global__ __launch_bounds__(512, 6) void deform_one(
    const float* __restrict__ x,        // [8][64][64][64]
    const float* __restrict__ woff_r,   // [64][18][12] f32
    const float* __restrict__ boff,     // [18]
    const u16*  __restrict__ wfrag,     // B-fragments bf16
    float* __restrict__ out) {          // [8][64][64][64]
  __shared__ __align__(16) u16 xos[64 * 296];  // 37888B: Phase-B partials (f32) then xo bf16 [64][296]
  __shared__ float4 gw[576];      // 9216B [n][w] validity-folded bilinear weights
  __shared__ u32    qq[576];      // 2304B [n][w] packed 0-based corner coords
  __shared__ float  offs_s[1152]; // 4608B [o][w]      total 54016B -> 3 blocks/CU

  int bh = blockIdx.x;
  int b = bh >> 6, h = bh & 63;
  int t = threadIdx.x;
  int wlane = t & 63;
  int wv = __builtin_amdgcn_readfirstlane(t >> 6);   // 0..7
  const float* xb = x + b * 262144;

  // ---- Phase B: offset conv, wave wv owns channels [8wv, 8wv+8), x from global ----
  {
    int w = wlane;
    bool lf = w > 0, rt = w < 63;
    float acc[18];
    #pragma unroll
    for (int o = 0; o < 18; ++o) acc[o] = 0.f;

    for (int cl = 0; cl < 8; ++cl) {
      int c = wv * 8 + cl;
      const float* xc = xb + c * 4096;
      float v[9];
      #pragma unroll
      for (int kh = 0; kh < 3; ++kh) {
        int hh = h + kh - 1;
        bool vr = (hh >= 0 && hh < 64);
        const float* row = xc + hh * 64;
        v[kh * 3 + 0] = (vr && lf) ? row[w - 1] : 0.f;
        v[kh * 3 + 1] = vr         ? row[w]     : 0.f;
        v[kh * 3 + 2] = (vr && rt) ? row[w + 1] : 0.f;
      }
      const float4* wc4 = (const float4*)(woff_r + c * 216);  // wave-uniform -> s_load
      #pragma unroll
      for (int o = 0; o < 18; ++o) {
        float4 wa  = wc4[o * 3 + 0];
        float4 wb  = wc4[o * 3 + 1];
        float4 wcv = wc4[o * 3 + 2];
        acc[o] += v[0]*wa.x + v[1]*wa.y + v[2]*wa.z + v[3]*wa.w
                + v[4]*wb.x + v[5]*wb.y + v[6]*wb.z + v[7]*wb.w
                + v[8]*wcv.x;
      }
    }

    // two-step cross-wave reduction in the xos region (aliased as f32)
    float* part = (float*)xos;                 // 4 regions x 1152 f32 = 18432B
    if (wv >= 4) {
      float* reg = part + (wv - 4) * 1152;
      #pragma unroll
      for (int o = 0; o < 18; ++o)
        reg[o * 64 + w] = acc[o];
    }
    __syncthreads();
    if (wv < 4) {
      float* reg = part + wv * 1152;
      #pragma unroll
      for (int o = 0; o < 18; ++o)
        reg[o * 64 + w] += acc[o];
    }
    __syncthreads();
    for (int i = t; i < 1152; i += 512) {
      int o = i >> 6;
      float s = boff[o] + part[i] + part[1152 + i] + part[2304 + i] + part[3456 + i];
      offs_s[i] = s;
    }
  }
  __syncthreads();

  // ---- Phase C: corners + bilinear weights, validity folded ----
  for (int p = t; p < 576; p += 512) {
    int n  = p >> 6;       // p = n*64 + w
    int ww = p & 63;
    float ox = offs_s[n * 64 + ww];
    float oy = offs_s[(9 + n) * 64 + ww];
    float px = (float)(h + (n / 3)) + ox;   // (h+1)+(n/3-1)+ox
    float py = (float)(ww + (n % 3)) + oy;
    float fx = floorf(px), fy = floorf(py);
    float pxc  = fminf(fmaxf(px, 0.f), 65.f);
    float pyc  = fminf(fmaxf(py, 0.f), 65.f);
    float fltx = fminf(fmaxf(fx, 0.f), 65.f);
    float flty = fminf(fmaxf(fy, 0.f), 65.f);
    float frbx = fminf(fmaxf(fx + 1.f, 0.f), 65.f);
    float frby = fminf(fmaxf(fy + 1.f, 0.f), 65.f);
    float ax = 1.f + fltx - pxc, bx = 1.f - frbx + pxc;
    float ay = 1.f + flty - pyc, by = 1.f - frby + pyc;
    float glt = ax * ay, grb = bx * by, glb = ax * by, grt = bx * ay;

    int ilt = (int)fltx, jlt = (int)flty, irb = (int)frbx, jrb = (int)frby;
    bool bi0 = (ilt >= 1 && ilt <= 64), bj0 = (jlt >= 1 && jlt <= 64);
    bool bi1 = (irb >= 1 && irb <= 64), bj1 = (jrb >= 1 && jrb <= 64);
    u32 i0 = bi0 ? (u32)(ilt - 1) : 0u;
    u32 j0 = bj0 ? (u32)(jlt - 1) : 0u;
    u32 i1 = bi1 ? (u32)(irb - 1) : 0u;
    u32 j1 = bj1 ? (u32)(jrb - 1) : 0u;
    gw[p] = make_float4((bi0 && bj0) ? glt : 0.f, (bi1 && bj1) ? grb : 0.f,
                        (bi0 && bj1) ? glb : 0.f, (bi1 && bj0) ? grt : 0.f);
    qq[p] = i0 | (j0 << 8) | (i1 << 16) | (j1 << 24);
  }
  __syncthreads();

  // ---- Phase D: 2 slices of 32 c: sample -> xo bf16 [w][k], MFMA dot ----
  int m0 = wv & 3;                      // w-tile
  int n0 = (wv >> 2) * 2;               // co-tiles n0, n0+1
  int aoff = (m0 * 16 + (wlane & 15)) * 296 + ((wlane >> 4) << 3);
  const s8v* Wf = (const s8v*)wfrag;    // [(nt*18+ks)*64 + lane]
  f4v acc0 = {0.f, 0.f, 0.f, 0.f}, acc1 = {0.f, 0.f, 0.f, 0.f};

  for (int s = 0; s < 2; ++s) {
    // sample: thread covers c_l = wv*4 .. wv*4+3, its lane's w, all 9 n
    int c_l0 = wv * 4;
    const float* xc0 = xb + (s * 32 + c_l0) * 4096;
    for (int n = 0; n < 9; ++n) {
      float4 g = gw[n * 64 + wlane];
      u32 q    = qq[n * 64 + wlane];
      int i0 = q & 255, j0 = (q >> 8) & 255, i1 = (q >> 16) & 255, j1 = q >> 24;
      int olt = i0 * 64 + j0, orb = i1 * 64 + j1;
      int olb = i0 * 64 + j1, ort = i1 * 64 + j0;
      #pragma unroll
      for (int j = 0; j < 4; ++j) {
        const float* xc = xc0 + j * 4096;
        float v = g.x * xc[olt] + g.y * xc[orb] + g.z * xc[olb] + g.w * xc[ort];
        xos[wlane * 296 + (c_l0 + j) * 9 + n] = f2bf(v);
      }
    }
    __syncthreads();

    // dot: 9 K-steps of 32; A from LDS (b128), B from global (coalesced 16B/lane)
    #pragma unroll
    for (int ksl = 0; ksl < 9; ++ksl) {
      s8v a = *(const s8v*)(xos + aoff + ksl * 32);
      int ks = s * 9 + ksl;
      s8v b0 = Wf[(n0 * 18 + ks) * 64 + wlane];
      s8v b1 = Wf[((n0 + 1) * 18 + ks) * 64 + wlane];
      acc0 = __builtin_amdgcn_mfma_f32_16x16x32_bf16(a, b0, acc0, 0, 0, 0);
      acc1 = __builtin_amdgcn_mfma_f32_16x16x32_bf16(a, b1, acc1, 0, 0, 0);
    }
    __syncthreads();
  }

  // ---- store: D layout col=lane&15 (co-local), row=quad*4+reg (w-local) ----
  float* ob = out + b * 262144 + h * 64;
  int quad = wlane >> 4;
  int w_b  = m0 * 16 + quad * 4;
  int co0  = n0 * 16 + (wlane & 15);
  int co1  = co0 + 16;
  #pragma unroll
  for (int r = 0; r < 4; ++r) {
    ob[co0 * 4096 + w_b + r] = acc0[r];
    ob[co1 * 4096 + w_b + r] = acc1[r];
  }
}

extern "C" void kernel_launch(void* const* d_in, const int* in_sizes, int n_in,
                              void* d_out, int out_size, void* d_ws, size_t ws_size,
                              hipStream_t stream) {
  const float *x = nullptr, *woff = nullptr, *boff = nullptr, *wconv = nullptr;
  for (int i = 0; i < n_in; ++i) {
    switch (in_sizes[i]) {
      case 2097152: x     = (const float*)d_in[i]; break;
      case 10368:   woff  = (const float*)d_in[i]; break;
      case 18:      boff  = (const float*)d_in[i]; break;
      case 36864:   wconv = (const float*)d_in[i]; break;
      default: break;
    }
  }
  if (!x)     x     = (const float*)d_in[0];
  if (!woff)  woff  = (const float*)d_in[1];
  if (!boff)  boff  = (const float*)d_in[2];
  if (!wconv) wconv = (const float*)d_in[3];
  float* out = (float*)d_out;

  u16*   wfrag  = (u16*)d_ws;                       // 73728 B
  float* woff_r = (float*)((char*)d_ws + 73728);    // 55296 B

  k0_prep<<<72, 256, 0, stream>>>(wconv, woff, wfrag, woff_r);
  deform_one<<<512, 512, 0, stream>>>(x, woff_r, boff, wfrag, out);
}

// Round 14
// 148.259 us; speedup vs baseline: 2.1378x; 1.1264x over previous
//
#include <hip/hip_runtime.h>
#include <hip/hip_bf16.h>

// B=8, C_IN=C_OUT=64, H=W=64, K=3, N=9, PAD=1; padded coords in [0,65]
// f32 in, f32 out. Semantics identical to R5-R13 (verified).
// R14 = R13 with the spill fixed: __launch_bounds__(512, 4) (VGPR cap 128).
// R13's (512,6) capped VGPR at 85 -> compiler spilled acc[18]+Phase-D state
// -> 140 MB scratch traffic. Grid is 512 blocks = 2/CU, so 6 waves/EU was
// unreachable anyway; 4 waves/EU matches the grid cap with zero spills.

typedef unsigned int u32;
typedef unsigned short u16;
typedef short s8v __attribute__((ext_vector_type(8)));     // 8 bf16 (4 VGPR)
typedef float f4v __attribute__((ext_vector_type(4)));     // MFMA acc

__device__ __forceinline__ u16 f2bf(float f) {
  u32 u = __builtin_bit_cast(u32, f);
  u32 r = (u + 0x7FFFu + ((u >> 16) & 1u)) >> 16;   // RNE, finite inputs
  return (u16)r;
}

// ---------- k0: weight prep ----------
// wfrag[nt][ks][lane][j] bf16: B-fragment for mfma_16x16x32_bf16
//   co = nt*16 + (lane&15), k = ks*32 + (lane>>4)*8 + j   (k = c*9+n order)
// woff_r[c][o][12] f32 (9 used, pad 12 for float4 alignment)
__global__ __launch_bounds__(256) void k0_prep(
    const float* __restrict__ wconv,  // [64][576]
    const float* __restrict__ woff,   // [18][64][9]
    u16* __restrict__ wfrag,          // 4*18*64*8 = 36864 bf16
    float* __restrict__ woff_r) {     // 64*216 f32
  int tid = blockIdx.x * 256 + threadIdx.x;   // grid 72*256 = 18432
  if (tid < 4608) {
    int nt = tid / 1152, ks = (tid / 64) % 18, lane = tid & 63;
    int co = nt * 16 + (lane & 15);
    int k0 = ks * 32 + ((lane >> 4) << 3);
    const float* src = wconv + co * 576 + k0;
    u16* dst = wfrag + tid * 8;
    #pragma unroll
    for (int j = 0; j < 8; ++j) dst[j] = f2bf(src[j]);
  }
  if (tid < 10368) {
    int o = tid / 576, c = (tid / 9) % 64, k = tid % 9;
    woff_r[c * 216 + o * 12 + k] = woff[tid];
  }
}

// ---------- fused main: one block per (b,h), 512 blocks x 512 threads ----------
__global__ __launch_bounds__(512, 4) void deform_one(
    const float* __restrict__ x,        // [8][64][64][64]
    const float* __restrict__ woff_r,   // [64][18][12] f32
    const float* __restrict__ boff,     // [18]
    const u16*  __restrict__ wfrag,     // B-fragments bf16
    float* __restrict__ out) {          // [8][64][64][64]
  __shared__ __align__(16) u16 xos[64 * 296];  // 37888B: Phase-B partials (f32) then xo bf16 [64][296]
  __shared__ float4 gw[576];      // 9216B [n][w] validity-folded bilinear weights
  __shared__ u32    qq[576];      // 2304B [n][w] packed 0-based corner coords
  __shared__ float  offs_s[1152]; // 4608B [o][w]      total 54016B

  int bh = blockIdx.x;
  int b = bh >> 6, h = bh & 63;
  int t = threadIdx.x;
  int wlane = t & 63;
  int wv = __builtin_amdgcn_readfirstlane(t >> 6);   // 0..7
  const float* xb = x + b * 262144;

  // ---- Phase B: offset conv, wave wv owns channels [8wv, 8wv+8), x from global ----
  {
    int w = wlane;
    bool lf = w > 0, rt = w < 63;
    float acc[18];
    #pragma unroll
    for (int o = 0; o < 18; ++o) acc[o] = 0.f;

    for (int cl = 0; cl < 8; ++cl) {
      int c = wv * 8 + cl;
      const float* xc = xb + c * 4096;
      float v[9];
      #pragma unroll
      for (int kh = 0; kh < 3; ++kh) {
        int hh = h + kh - 1;
        bool vr = (hh >= 0 && hh < 64);
        const float* row = xc + hh * 64;
        v[kh * 3 + 0] = (vr && lf) ? row[w - 1] : 0.f;
        v[kh * 3 + 1] = vr         ? row[w]     : 0.f;
        v[kh * 3 + 2] = (vr && rt) ? row[w + 1] : 0.f;
      }
      const float4* wc4 = (const float4*)(woff_r + c * 216);  // wave-uniform -> s_load
      #pragma unroll
      for (int o = 0; o < 18; ++o) {
        float4 wa  = wc4[o * 3 + 0];
        float4 wb  = wc4[o * 3 + 1];
        float4 wcv = wc4[o * 3 + 2];
        acc[o] += v[0]*wa.x + v[1]*wa.y + v[2]*wa.z + v[3]*wa.w
                + v[4]*wb.x + v[5]*wb.y + v[6]*wb.z + v[7]*wb.w
                + v[8]*wcv.x;
      }
    }

    // two-step cross-wave reduction in the xos region (aliased as f32)
    float* part = (float*)xos;                 // 4 regions x 1152 f32 = 18432B
    if (wv >= 4) {
      float* reg = part + (wv - 4) * 1152;
      #pragma unroll
      for (int o = 0; o < 18; ++o)
        reg[o * 64 + w] = acc[o];
    }
    __syncthreads();
    if (wv < 4) {
      float* reg = part + wv * 1152;
      #pragma unroll
      for (int o = 0; o < 18; ++o)
        reg[o * 64 + w] += acc[o];
    }
    __syncthreads();
    for (int i = t; i < 1152; i += 512) {
      int o = i >> 6;
      float s = boff[o] + part[i] + part[1152 + i] + part[2304 + i] + part[3456 + i];
      offs_s[i] = s;
    }
  }
  __syncthreads();

  // ---- Phase C: corners + bilinear weights, validity folded ----
  for (int p = t; p < 576; p += 512) {
    int n  = p >> 6;       // p = n*64 + w
    int ww = p & 63;
    float ox = offs_s[n * 64 + ww];
    float oy = offs_s[(9 + n) * 64 + ww];
    float px = (float)(h + (n / 3)) + ox;   // (h+1)+(n/3-1)+ox
    float py = (float)(ww + (n % 3)) + oy;
    float fx = floorf(px), fy = floorf(py);
    float pxc  = fminf(fmaxf(px, 0.f), 65.f);
    float pyc  = fminf(fmaxf(py, 0.f), 65.f);
    float fltx = fminf(fmaxf(fx, 0.f), 65.f);
    float flty = fminf(fmaxf(fy, 0.f), 65.f);
    float frbx = fminf(fmaxf(fx + 1.f, 0.f), 65.f);
    float frby = fminf(fmaxf(fy + 1.f, 0.f), 65.f);
    float ax = 1.f + fltx - pxc, bx = 1.f - frbx + pxc;
    float ay = 1.f + flty - pyc, by = 1.f - frby + pyc;
    float glt = ax * ay, grb = bx * by, glb = ax * by, grt = bx * ay;

    int ilt = (int)fltx, jlt = (int)flty, irb = (int)frbx, jrb = (int)frby;
    bool bi0 = (ilt >= 1 && ilt <= 64), bj0 = (jlt >= 1 && jlt <= 64);
    bool bi1 = (irb >= 1 && irb <= 64), bj1 = (jrb >= 1 && jrb <= 64);
    u32 i0 = bi0 ? (u32)(ilt - 1) : 0u;
    u32 j0 = bj0 ? (u32)(jlt - 1) : 0u;
    u32 i1 = bi1 ? (u32)(irb - 1) : 0u;
    u32 j1 = bj1 ? (u32)(jrb - 1) : 0u;
    gw[p] = make_float4((bi0 && bj0) ? glt : 0.f, (bi1 && bj1) ? grb : 0.f,
                        (bi0 && bj1) ? glb : 0.f, (bi1 && bj0) ? grt : 0.f);
    qq[p] = i0 | (j0 << 8) | (i1 << 16) | (j1 << 24);
  }
  __syncthreads();

  // ---- Phase D: 2 slices of 32 c: sample -> xo bf16 [w][k], MFMA dot ----
  int m0 = wv & 3;                      // w-tile
  int n0 = (wv >> 2) * 2;               // co-tiles n0, n0+1
  int aoff = (m0 * 16 + (wlane & 15)) * 296 + ((wlane >> 4) << 3);
  const s8v* Wf = (const s8v*)wfrag;    // [(nt*18+ks)*64 + lane]
  f4v acc0 = {0.f, 0.f, 0.f, 0.f}, acc1 = {0.f, 0.f, 0.f, 0.f};

  for (int s = 0; s < 2; ++s) {
    // sample: thread covers c_l = wv*4 .. wv*4+3, its lane's w, all 9 n
    int c_l0 = wv * 4;
    const float* xc0 = xb + (s * 32 + c_l0) * 4096;
    for (int n = 0; n < 9; ++n) {
      float4 g = gw[n * 64 + wlane];
      u32 q    = qq[n * 64 + wlane];
      int i0 = q & 255, j0 = (q >> 8) & 255, i1 = (q >> 16) & 255, j1 = q >> 24;
      int olt = i0 * 64 + j0, orb = i1 * 64 + j1;
      int olb = i0 * 64 + j1, ort = i1 * 64 + j0;
      #pragma unroll
      for (int j = 0; j < 4; ++j) {
        const float* xc = xc0 + j * 4096;
        float v = g.x * xc[olt] + g.y * xc[orb] + g.z * xc[olb] + g.w * xc[ort];
        xos[wlane * 296 + (c_l0 + j) * 9 + n] = f2bf(v);
      }
    }
    __syncthreads();

    // dot: 9 K-steps of 32; A from LDS (b128), B from global (coalesced 16B/lane)
    #pragma unroll
    for (int ksl = 0; ksl < 9; ++ksl) {
      s8v a = *(const s8v*)(xos + aoff + ksl * 32);
      int ks = s * 9 + ksl;
      s8v b0 = Wf[(n0 * 18 + ks) * 64 + wlane];
      s8v b1 = Wf[((n0 + 1) * 18 + ks) * 64 + wlane];
      acc0 = __builtin_amdgcn_mfma_f32_16x16x32_bf16(a, b0, acc0, 0, 0, 0);
      acc1 = __builtin_amdgcn_mfma_f32_16x16x32_bf16(a, b1, acc1, 0, 0, 0);
    }
    __syncthreads();
  }

  // ---- store: D layout col=lane&15 (co-local), row=quad*4+reg (w-local) ----
  float* ob = out + b * 262144 + h * 64;
  int quad = wlane >> 4;
  int w_b  = m0 * 16 + quad * 4;
  int co0  = n0 * 16 + (wlane & 15);
  int co1  = co0 + 16;
  #pragma unroll
  for (int r = 0; r < 4; ++r) {
    ob[co0 * 4096 + w_b + r] = acc0[r];
    ob[co1 * 4096 + w_b + r] = acc1[r];
  }
}

extern "C" void kernel_launch(void* const* d_in, const int* in_sizes, int n_in,
                              void* d_out, int out_size, void* d_ws, size_t ws_size,
                              hipStream_t stream) {
  const float *x = nullptr, *woff = nullptr, *boff = nullptr, *wconv = nullptr;
  for (int i = 0; i < n_in; ++i) {
    switch (in_sizes[i]) {
      case 2097152: x     = (const float*)d_in[i]; break;
      case 10368:   woff  = (const float*)d_in[i]; break;
      case 18:      boff  = (const float*)d_in[i]; break;
      case 36864:   wconv = (const float*)d_in[i]; break;
      default: break;
    }
  }
  if (!x)     x     = (const float*)d_in[0];
  if (!woff)  woff  = (const float*)d_in[1];
  if (!boff)  boff  = (const float*)d_in[2];
  if (!wconv) wconv = (const float*)d_in[3];
  float* out = (float*)d_out;

  u16*   wfrag  = (u16*)d_ws;                       // 73728 B
  float* woff_r = (float*)((char*)d_ws + 73728);    // 55296 B

  k0_prep<<<72, 256, 0, stream>>>(wconv, woff, wfrag, woff_r);
  deform_one<<<512, 512, 0, stream>>>(x, woff_r, boff, wfrag, out);
}